// Round 7
// baseline (186.864 us; speedup 1.0000x reference)
//
#include <hip/hip_runtime.h>

// FiLM block, MI355X. I/O fp32; compute bf16 MFMA (A=weights, B=tokens,
// C col=token), fp32 accum. R7 = R6 (validated) + 2-wide token super-tiles
// (every W1/W2 LDS fragment feeds 2 MFMAs), W0 A-frags from a global bf16
// image (L1-hot), x converted in-register (prep's x-pass deleted).
// R5's corruption root-caused to __restrict__ on the LDS h-pointer while
// reading the same rows via smem (aliasing lie -> illegal reorder under the
// unrolled super-tile body). Here: NO restrict on LDS pointers, plain loop.
#define NTOK  32768
#define CIN   64
#define HDIM  128
#define O_CH  16
#define F2    16
#define SLOPE 0.01f
#define EPS   1e-5f

// LDS (shorts): W1' + W2' (padded rows: 16B-aligned starts), then h-buffer
// 128 rows (32 tokens/wave x 4 waves).
#define SW1_STRIDE 136
#define SW2_STRIDE 136
#define SH_STRIDE  136
#define SW1_OFF 0                        // 128 x 136 = 17408
#define SW2_OFF 17408                    // 16  x 136 = 2176
#define WIMG_SHORTS (17408 + 2176)       // 19584 shorts per o
#define SH_OFF  WIMG_SHORTS
#define SMEM_TOT (WIMG_SHORTS + 128 * SH_STRIDE)  // 36992 sh = 73984 B -> 2 blk/CU

// d_ws layout (bytes); ~0.9 MB total.
#define W0G_OFF    0
#define W0G_BYTES  ((size_t)O_CH * HDIM * CIN * 2)           // 262144
#define WIMG_OFF   W0G_BYTES
#define WIMG_BYTES ((size_t)O_CH * WIMG_SHORTS * 2)          // 626688
#define B0F_OFF    (WIMG_OFF + WIMG_BYTES)
#define B0F_BYTES  ((size_t)O_CH * HDIM * 4)
#define B1F_OFF    (B0F_OFF + B0F_BYTES)
#define B1F_BYTES  ((size_t)O_CH * HDIM * 4)
#define B2F_OFF    (B1F_OFF + B1F_BYTES)
#define B2F_BYTES  ((size_t)O_CH * F2 * 4)

typedef __attribute__((ext_vector_type(8))) short bf16x8;
typedef __attribute__((ext_vector_type(4))) short bf16x4;
typedef __attribute__((ext_vector_type(4))) float f32x4;

__device__ __forceinline__ unsigned short f2b(float f) {
  union { float f; unsigned int i; } v;
  v.f = f;
  unsigned int i = v.i;
  unsigned int r = (i + 0x7fffu + ((i >> 16) & 1u)) >> 16;  // RNE
  return (unsigned short)r;
}
__device__ __forceinline__ float leaky(float t) {
  return (t >= 0.f) ? t : SLOPE * t;
}
__device__ __forceinline__ bf16x8 cvt8(const float* p) {
  float4 a = *(const float4*)p;
  float4 b = *(const float4*)(p + 4);
  bf16x8 r;
  r[0] = (short)f2b(a.x); r[1] = (short)f2b(a.y);
  r[2] = (short)f2b(a.z); r[3] = (short)f2b(a.w);
  r[4] = (short)f2b(b.x); r[5] = (short)f2b(b.y);
  r[6] = (short)f2b(b.z); r[7] = (short)f2b(b.w);
  return r;
}
__device__ __forceinline__ bf16x8 cvt8s(const float* p, const float* s) {
  bf16x8 r;
#pragma unroll
  for (int i = 0; i < 8; ++i) r[i] = (short)f2b(p[i] * s[i]);
  return r;
}

// leaky + LayerNorm on C-layout (col=token=lane&15, row=h). Lane holds 32 h
// of one token; butterfly xor 16,32 finishes the 128-sum. Stores (t-mu)*rs
// bf16 to LDS h[shrow][h] via ds_write_b64. NOTE: sh is NOT restrict --
// layer-1/2 read these rows through smem; may-alias enforces ordering.
__device__ __forceinline__ void leaky_ln_store(
    const f32x4* acc, unsigned short* sh, int shrow, int quad) {
  float v[8][4];
  float s1 = 0.f, s2 = 0.f;
#pragma unroll
  for (int nt = 0; nt < 8; ++nt) {
#pragma unroll
    for (int r = 0; r < 4; ++r) {
      float t = leaky(acc[nt][r]);        // bias folded into C-init
      v[nt][r] = t;
      s1 += t;
      s2 += t * t;
    }
  }
  s1 += __shfl_xor(s1, 16); s2 += __shfl_xor(s2, 16);
  s1 += __shfl_xor(s1, 32); s2 += __shfl_xor(s2, 32);
  float mu = s1 * (1.0f / 128.0f);
  float var = s2 * (1.0f / 128.0f) - mu * mu;
  float rs = rsqrtf(var + EPS);
#pragma unroll
  for (int nt = 0; nt < 8; ++nt) {
    bf16x4 p;
#pragma unroll
    for (int r = 0; r < 4; ++r)
      p[r] = (short)f2b((v[nt][r] - mu) * rs);
    *(bf16x4*)&sh[shrow * SH_STRIDE + nt * 16 + quad * 4] = p;
  }
}

// prep: 16 blocks, one per o: W0 bf16 flat image (global A-frags), W1'/W2'
// gamma-folded padded images, folded biases. (x-conversion deleted in R7.)
__global__ __launch_bounds__(256) void prep(
    const float* __restrict__ W0, const float* __restrict__ b0,
    const float* __restrict__ g0, const float* __restrict__ be0,
    const float* __restrict__ W1, const float* __restrict__ b1,
    const float* __restrict__ g1, const float* __restrict__ be1,
    const float* __restrict__ W2, const float* __restrict__ b2,
    unsigned short* __restrict__ w0g, unsigned short* __restrict__ wimg,
    float* __restrict__ b0f, float* __restrict__ b1f,
    float* __restrict__ b2f) {
  const int o = blockIdx.x, tid = threadIdx.x;
  __shared__ float sg0[HDIM], sbe0[HDIM], sg1[HDIM], sbe1[HDIM];
  if (tid < 128) {
    sg0[tid]  = g0 [o * HDIM + tid];
    sbe0[tid] = be0[o * HDIM + tid];
    sg1[tid]  = g1 [o * HDIM + tid];
    sbe1[tid] = be1[o * HDIM + tid];
  }
  __syncthreads();
  const float* w0 = W0 + (size_t)o * HDIM * CIN;
  for (int c = tid; c < (HDIM * CIN) / 8; c += 256)            // 1024
    *(bf16x8*)&w0g[(size_t)o * HDIM * CIN + c * 8] = cvt8(w0 + c * 8);
  unsigned short* img = wimg + (size_t)o * WIMG_SHORTS;
  const float* w1 = W1 + (size_t)o * HDIM * HDIM;
  for (int c = tid; c < (HDIM * HDIM) / 8; c += 256) {         // 2048
    int n = c >> 4, k8 = c & 15;
    *(bf16x8*)&img[SW1_OFF + n * SW1_STRIDE + k8 * 8] =
        cvt8s(w1 + c * 8, sg0 + k8 * 8);             // W1' = W1 * g0[k]
  }
  const float* w2 = W2 + (size_t)o * F2 * HDIM;
  for (int c = tid; c < (F2 * HDIM) / 8; c += 256) {           // 256
    int n = c >> 4, k8 = c & 15;
    *(bf16x8*)&img[SW2_OFF + n * SW2_STRIDE + k8 * 8] =
        cvt8s(w2 + c * 8, sg1 + k8 * 8);             // W2' = W2 * g1[k]
  }
  if (tid < 128) {
    b0f[o * HDIM + tid] = b0[o * HDIM + tid];
    float d = 0.f;
    const float* w1r = w1 + (size_t)tid * HDIM;
    for (int k = 0; k < HDIM; ++k) d += w1r[k] * sbe0[k];
    b1f[o * HDIM + tid] = b1[o * HDIM + tid] + d;    // b1' = b1 + W1*be0
  } else if (tid < 144) {
    int f = tid - 128;
    float d = 0.f;
    const float* w2r = w2 + (size_t)f * HDIM;
    for (int k = 0; k < HDIM; ++k) d += w2r[k] * sbe1[k];
    b2f[o * F2 + f] = b2[o * F2 + f] + d;            // b2' = b2 + W2*be1
  }
}

// film_main: block = one o x 256 tokens; wave = 64 tokens as 2 super-tiles
// of 32 (2 MFMA m-tiles sharing every weight A-fragment).
// bid = q*128 + o*8 + c: 16 o-blocks of token-group q*8+c share XCD c within
// a 121-bid window -> output sector writes combine in that XCD's L2 [R6:
// WRITE_SIZE == ideal].
__global__ __launch_bounds__(256, 2) void film_main(
    const float* __restrict__ x,
    const unsigned short* __restrict__ w0g,
    const unsigned short* __restrict__ wimg,
    const float* __restrict__ b0f, const float* __restrict__ b1f,
    const float* __restrict__ b2f,
    float* __restrict__ out) {
  __shared__ unsigned short smem[SMEM_TOT];
  const int tid = threadIdx.x;
  const int c   = blockIdx.x & 7;
  const int o   = (blockIdx.x >> 3) & 15;
  const int q   = blockIdx.x >> 7;
  const int tok0 = (q * 8 + c) * 256;

  {  // stage W1'+W2' image (39.2 KB contiguous copy)
    const bf16x8* src = (const bf16x8*)(wimg + (size_t)o * WIMG_SHORTS);
    for (int i = tid; i < WIMG_SHORTS / 8; i += 256)
      *(bf16x8*)&smem[i * 8] = src[i];
  }

  const int lane = tid & 63;
  const int wave = tid >> 6;
  const int lo16 = lane & 15;
  const int quad = lane >> 4;
  unsigned short* sh = smem + SH_OFF;   // h-buffer (no restrict anywhere)

  // per-lane bias C-init fragments: h-dim = nt*16 + quad*4 + r
  f32x4 bias0[8], bias1[8];
#pragma unroll
  for (int nt = 0; nt < 8; ++nt) {
    bias0[nt] = *(const f32x4*)&b0f[o * HDIM + nt * 16 + quad * 4];
    bias1[nt] = *(const f32x4*)&b1f[o * HDIM + nt * 16 + quad * 4];
  }
  const f32x4 bias2 = *(const f32x4*)&b2f[o * F2 + quad * 4];
  const unsigned short* w0o = w0g + (size_t)o * HDIM * CIN;
  __syncthreads();

  for (int st = 0; st < 2; ++st) {           // plain loop (see R5 post-mortem)
    const int tb = tok0 + wave * 64 + st * 32;   // super-tile: 32 tokens
    const int shbase = wave * 32;                // wave's 32 h-rows

    // ---- Layer 0: A=W0 (global bf16, L1-hot), B=x (fp32 -> bf16 in-reg)
    f32x4 acc0[8], acc1[8];
#pragma unroll
    for (int nt = 0; nt < 8; ++nt) { acc0[nt] = bias0[nt]; acc1[nt] = bias0[nt]; }
#pragma unroll
    for (int ks = 0; ks < 2; ++ks) {
      bf16x8 bx0 = cvt8(&x[(size_t)(tb + lo16) * CIN + ks * 32 + quad * 8]);
      bf16x8 bx1 = cvt8(&x[(size_t)(tb + 16 + lo16) * CIN + ks * 32 + quad * 8]);
#pragma unroll
      for (int nt = 0; nt < 8; ++nt) {
        bf16x8 a = *(const bf16x8*)&w0o[(size_t)(nt * 16 + lo16) * CIN + ks * 32 + quad * 8];
        acc0[nt] = __builtin_amdgcn_mfma_f32_16x16x32_bf16(a, bx0, acc0[nt], 0, 0, 0);
        acc1[nt] = __builtin_amdgcn_mfma_f32_16x16x32_bf16(a, bx1, acc1[nt], 0, 0, 0);
      }
    }
    leaky_ln_store(acc0, sh, shbase + lo16, quad);
    leaky_ln_store(acc1, sh, shbase + 16 + lo16, quad);

    // ---- Layer 1: A=W1' (LDS), B=h; A-frags shared across the 2 m-tiles
#pragma unroll
    for (int nt = 0; nt < 8; ++nt) { acc0[nt] = bias1[nt]; acc1[nt] = bias1[nt]; }
#pragma unroll
    for (int ks = 0; ks < 4; ++ks) {
      bf16x8 bh0 = *(const bf16x8*)&sh[(shbase + lo16) * SH_STRIDE + ks * 32 + quad * 8];
      bf16x8 bh1 = *(const bf16x8*)&sh[(shbase + 16 + lo16) * SH_STRIDE + ks * 32 + quad * 8];
#pragma unroll
      for (int nt = 0; nt < 8; ++nt) {
        bf16x8 a = *(const bf16x8*)
            &smem[SW1_OFF + (nt * 16 + lo16) * SW1_STRIDE + ks * 32 + quad * 8];
        acc0[nt] = __builtin_amdgcn_mfma_f32_16x16x32_bf16(a, bh0, acc0[nt], 0, 0, 0);
        acc1[nt] = __builtin_amdgcn_mfma_f32_16x16x32_bf16(a, bh1, acc1[nt], 0, 0, 0);
      }
    }
    leaky_ln_store(acc0, sh, shbase + lo16, quad);
    leaky_ln_store(acc1, sh, shbase + 16 + lo16, quad);

    // ---- Layer 2: A=W2' (LDS), B=h -> C[col=token][row=f]
    f32x4 acc2a = bias2, acc2b = bias2;
#pragma unroll
    for (int ks = 0; ks < 4; ++ks) {
      bf16x8 bh0 = *(const bf16x8*)&sh[(shbase + lo16) * SH_STRIDE + ks * 32 + quad * 8];
      bf16x8 bh1 = *(const bf16x8*)&sh[(shbase + 16 + lo16) * SH_STRIDE + ks * 32 + quad * 8];
      bf16x8 a = *(const bf16x8*)
          &smem[SW2_OFF + lo16 * SW2_STRIDE + ks * 32 + quad * 8];
      acc2a = __builtin_amdgcn_mfma_f32_16x16x32_bf16(a, bh0, acc2a, 0, 0, 0);
      acc2b = __builtin_amdgcn_mfma_f32_16x16x32_bf16(a, bh1, acc2b, 0, 0, 0);
    }
    // direct fp32 out[tok][f][o] (mapping validated R6)
    {
      const size_t ta = (size_t)(tb + lo16) * (F2 * O_CH);
      const size_t tbf = (size_t)(tb + 16 + lo16) * (F2 * O_CH);
#pragma unroll
      for (int r = 0; r < 4; ++r) {
        out[ta  + (quad * 4 + r) * O_CH + o] = leaky(acc2a[r]);
        out[tbf + (quad * 4 + r) * O_CH + o] = leaky(acc2b[r]);
      }
    }
  }
}

extern "C" void kernel_launch(void* const* d_in, const int* in_sizes, int n_in,
                              void* d_out, int out_size, void* d_ws, size_t ws_size,
                              hipStream_t stream) {
  (void)in_sizes; (void)n_in; (void)out_size; (void)ws_size;
  const float* x   = (const float*)d_in[0];
  const float* W0  = (const float*)d_in[1];
  const float* b0  = (const float*)d_in[2];
  const float* g0  = (const float*)d_in[3];
  const float* be0 = (const float*)d_in[4];
  const float* W1  = (const float*)d_in[5];
  const float* b1  = (const float*)d_in[6];
  const float* g1  = (const float*)d_in[7];
  const float* be1 = (const float*)d_in[8];
  const float* W2  = (const float*)d_in[9];
  const float* b2  = (const float*)d_in[10];

  unsigned short* w0g  = (unsigned short*)((char*)d_ws + W0G_OFF);
  unsigned short* wimg = (unsigned short*)((char*)d_ws + WIMG_OFF);
  float* b0f = (float*)((char*)d_ws + B0F_OFF);
  float* b1f = (float*)((char*)d_ws + B1F_OFF);
  float* b2f = (float*)((char*)d_ws + B2F_OFF);

  prep<<<dim3(16), dim3(256), 0, stream>>>(
      W0, b0, g0, be0, W1, b1, g1, be1, W2, b2, w0g, wimg, b0f, b1f, b2f);
  film_main<<<dim3(O_CH * (NTOK / 256)), dim3(256), 0, stream>>>(
      x, w0g, wimg, b0f, b1f, b2f, (float*)d_out);
}

// Round 8
// 178.735 us; speedup vs baseline: 1.0455x; 1.0455x over previous
//
#include <hip/hip_runtime.h>

// FiLM block, MI355X. I/O fp32; compute bf16 MFMA (A=weights, B=tokens,
// C col=token), fp32 accum. R8 = validated pieces only:
//  - R7's 2-wide token super-tiles (W1/W2 LDS frags shared by 2 MFMAs)
//  - R6's pre-converted bf16 x (B-frags = single dwordx4, prefetchable)
//  - W0 A-frags hoisted to REGISTERS (loaded once/block from w0g image;
//    same addresses R7 used per-use -> pure scheduling change)
// R7 lesson: per-use global loads in the layer-0 path stall all waves at the
// same phase (8 waves/CU can't hide it) -> keep hot loop on LDS/registers.
#define NTOK  32768
#define CIN   64
#define HDIM  128
#define O_CH  16
#define F2    16
#define SLOPE 0.01f
#define EPS   1e-5f

// LDS (shorts): W1' + W2' (padded rows), h-buffer 128 rows.
#define SW1_STRIDE 136
#define SW2_STRIDE 136
#define SH_STRIDE  136
#define SW1_OFF 0                        // 128 x 136 = 17408
#define SW2_OFF 17408                    // 16  x 136 = 2176
#define WIMG_SHORTS (17408 + 2176)       // 19584 shorts per o
#define SH_OFF  WIMG_SHORTS
#define SMEM_TOT (WIMG_SHORTS + 128 * SH_STRIDE)  // 36992 sh = 73984 B -> 2 blk/CU

// d_ws layout (bytes); ~5.1 MB total.
#define W0G_OFF    0
#define W0G_BYTES  ((size_t)O_CH * HDIM * CIN * 2)           // 262144
#define WIMG_OFF   W0G_BYTES
#define WIMG_BYTES ((size_t)O_CH * WIMG_SHORTS * 2)          // 626688
#define XBF_OFF    (WIMG_OFF + WIMG_BYTES)
#define XBF_BYTES  ((size_t)NTOK * CIN * 2)                  // 4194304
#define B0F_OFF    (XBF_OFF + XBF_BYTES)
#define B0F_BYTES  ((size_t)O_CH * HDIM * 4)
#define B1F_OFF    (B0F_OFF + B0F_BYTES)
#define B1F_BYTES  ((size_t)O_CH * HDIM * 4)
#define B2F_OFF    (B1F_OFF + B1F_BYTES)
#define B2F_BYTES  ((size_t)O_CH * F2 * 4)

typedef __attribute__((ext_vector_type(8))) short bf16x8;
typedef __attribute__((ext_vector_type(4))) short bf16x4;
typedef __attribute__((ext_vector_type(4))) float f32x4;

__device__ __forceinline__ unsigned short f2b(float f) {
  union { float f; unsigned int i; } v;
  v.f = f;
  unsigned int i = v.i;
  unsigned int r = (i + 0x7fffu + ((i >> 16) & 1u)) >> 16;  // RNE
  return (unsigned short)r;
}
__device__ __forceinline__ float leaky(float t) {
  return (t >= 0.f) ? t : SLOPE * t;
}
__device__ __forceinline__ bf16x8 cvt8(const float* p) {
  float4 a = *(const float4*)p;
  float4 b = *(const float4*)(p + 4);
  bf16x8 r;
  r[0] = (short)f2b(a.x); r[1] = (short)f2b(a.y);
  r[2] = (short)f2b(a.z); r[3] = (short)f2b(a.w);
  r[4] = (short)f2b(b.x); r[5] = (short)f2b(b.y);
  r[6] = (short)f2b(b.z); r[7] = (short)f2b(b.w);
  return r;
}
__device__ __forceinline__ bf16x8 cvt8s(const float* p, const float* s) {
  bf16x8 r;
#pragma unroll
  for (int i = 0; i < 8; ++i) r[i] = (short)f2b(p[i] * s[i]);
  return r;
}

// leaky + LayerNorm on C-layout (col=token=lane&15, row=h). Lane holds 32 h
// of one token; butterfly xor 16,32 finishes the 128-sum. bf16 ds_write_b64.
// sh NOT restrict (layer-1/2 read these rows via smem; R5 post-mortem).
__device__ __forceinline__ void leaky_ln_store(
    const f32x4* acc, unsigned short* sh, int shrow, int quad) {
  float v[8][4];
  float s1 = 0.f, s2 = 0.f;
#pragma unroll
  for (int nt = 0; nt < 8; ++nt) {
#pragma unroll
    for (int r = 0; r < 4; ++r) {
      float t = leaky(acc[nt][r]);        // bias folded into C-init
      v[nt][r] = t;
      s1 += t;
      s2 += t * t;
    }
  }
  s1 += __shfl_xor(s1, 16); s2 += __shfl_xor(s2, 16);
  s1 += __shfl_xor(s1, 32); s2 += __shfl_xor(s2, 32);
  float mu = s1 * (1.0f / 128.0f);
  float var = s2 * (1.0f / 128.0f) - mu * mu;
  float rs = rsqrtf(var + EPS);
#pragma unroll
  for (int nt = 0; nt < 8; ++nt) {
    bf16x4 p;
#pragma unroll
    for (int r = 0; r < 4; ++r)
      p[r] = (short)f2b((v[nt][r] - mu) * rs);
    *(bf16x4*)&sh[shrow * SH_STRIDE + nt * 16 + quad * 4] = p;
  }
}

// prep: blocks 0..15 -> per-o images (W0 bf16 flat; W1'/W2' gamma-folded;
// folded biases). blocks 16+ -> x fp32 -> bf16.
__global__ __launch_bounds__(256) void prep(
    const float* __restrict__ x,
    const float* __restrict__ W0, const float* __restrict__ b0,
    const float* __restrict__ g0, const float* __restrict__ be0,
    const float* __restrict__ W1, const float* __restrict__ b1,
    const float* __restrict__ g1, const float* __restrict__ be1,
    const float* __restrict__ W2, const float* __restrict__ b2,
    unsigned short* __restrict__ w0g, unsigned short* __restrict__ wimg,
    unsigned short* __restrict__ xbf,
    float* __restrict__ b0f, float* __restrict__ b1f,
    float* __restrict__ b2f) {
  const int bid = blockIdx.x, tid = threadIdx.x;
  if (bid < 16) {
    const int o = bid;
    __shared__ float sg0[HDIM], sbe0[HDIM], sg1[HDIM], sbe1[HDIM];
    if (tid < 128) {
      sg0[tid]  = g0 [o * HDIM + tid];
      sbe0[tid] = be0[o * HDIM + tid];
      sg1[tid]  = g1 [o * HDIM + tid];
      sbe1[tid] = be1[o * HDIM + tid];
    }
    __syncthreads();
    const float* w0 = W0 + (size_t)o * HDIM * CIN;
    for (int c = tid; c < (HDIM * CIN) / 8; c += 256)          // 1024
      *(bf16x8*)&w0g[(size_t)o * HDIM * CIN + c * 8] = cvt8(w0 + c * 8);
    unsigned short* img = wimg + (size_t)o * WIMG_SHORTS;
    const float* w1 = W1 + (size_t)o * HDIM * HDIM;
    for (int c = tid; c < (HDIM * HDIM) / 8; c += 256) {       // 2048
      int n = c >> 4, k8 = c & 15;
      *(bf16x8*)&img[SW1_OFF + n * SW1_STRIDE + k8 * 8] =
          cvt8s(w1 + c * 8, sg0 + k8 * 8);           // W1' = W1 * g0[k]
    }
    const float* w2 = W2 + (size_t)o * F2 * HDIM;
    for (int c = tid; c < (F2 * HDIM) / 8; c += 256) {         // 256
      int n = c >> 4, k8 = c & 15;
      *(bf16x8*)&img[SW2_OFF + n * SW2_STRIDE + k8 * 8] =
          cvt8s(w2 + c * 8, sg1 + k8 * 8);           // W2' = W2 * g1[k]
    }
    if (tid < 128) {
      b0f[o * HDIM + tid] = b0[o * HDIM + tid];
      float d = 0.f;
      const float* w1r = w1 + (size_t)tid * HDIM;
      for (int k = 0; k < HDIM; ++k) d += w1r[k] * sbe0[k];
      b1f[o * HDIM + tid] = b1[o * HDIM + tid] + d;  // b1' = b1 + W1*be0
    } else if (tid < 144) {
      int f = tid - 128;
      float d = 0.f;
      const float* w2r = w2 + (size_t)f * HDIM;
      for (int k = 0; k < HDIM; ++k) d += w2r[k] * sbe1[k];
      b2f[o * F2 + f] = b2[o * F2 + f] + d;          // b2' = b2 + W2*be1
    }
  } else {
    int idx = (bid - 16) * 256 + tid;
    *(bf16x8*)&xbf[(size_t)idx * 8] = cvt8(x + (size_t)idx * 8);
  }
}

// film_main: block = one o x 256 tokens; wave = 64 tokens as 2 super-tiles
// of 32. W0 A-frags in registers; W1'/W2' from LDS (frags shared 2-ways);
// x from bf16 image. bid = q*128 + o*8 + c (XCD write-combine, R6-validated).
__global__ __launch_bounds__(256, 2) void film_main(
    const unsigned short* __restrict__ xbf,
    const unsigned short* __restrict__ w0g,
    const unsigned short* __restrict__ wimg,
    const float* __restrict__ b0f, const float* __restrict__ b1f,
    const float* __restrict__ b2f,
    float* __restrict__ out) {
  __shared__ unsigned short smem[SMEM_TOT];
  const int tid = threadIdx.x;
  const int c   = blockIdx.x & 7;
  const int o   = (blockIdx.x >> 3) & 15;
  const int q   = blockIdx.x >> 7;
  const int tok0 = (q * 8 + c) * 256;

  const int lane = tid & 63;
  const int wave = tid >> 6;
  const int lo16 = lane & 15;
  const int quad = lane >> 4;
  unsigned short* sh = smem + SH_OFF;

  // W0 A-frags -> registers, once per block (addresses validated R7)
  const unsigned short* w0o = w0g + (size_t)o * HDIM * CIN;
  bf16x8 w0f[2][8];
#pragma unroll
  for (int ks = 0; ks < 2; ++ks)
#pragma unroll
    for (int nt = 0; nt < 8; ++nt)
      w0f[ks][nt] = *(const bf16x8*)
          &w0o[(size_t)(nt * 16 + lo16) * CIN + ks * 32 + quad * 8];

  {  // stage W1'+W2' image (39.2 KB contiguous copy)
    const bf16x8* src = (const bf16x8*)(wimg + (size_t)o * WIMG_SHORTS);
    for (int i = tid; i < WIMG_SHORTS / 8; i += 256)
      *(bf16x8*)&smem[i * 8] = src[i];
  }

  // per-lane bias C-init fragments: h-dim = nt*16 + quad*4 + r
  f32x4 bias0[8], bias1[8];
#pragma unroll
  for (int nt = 0; nt < 8; ++nt) {
    bias0[nt] = *(const f32x4*)&b0f[o * HDIM + nt * 16 + quad * 4];
    bias1[nt] = *(const f32x4*)&b1f[o * HDIM + nt * 16 + quad * 4];
  }
  const f32x4 bias2 = *(const f32x4*)&b2f[o * F2 + quad * 4];
  __syncthreads();

  for (int st = 0; st < 2; ++st) {           // plain loop (R5 post-mortem)
    const int tb = tok0 + wave * 64 + st * 32;   // super-tile: 32 tokens
    const int shbase = wave * 32;                // wave's 32 h-rows

    // ---- Layer 0: A=W0 (registers), B=x (bf16 image, single dwordx4 loads)
    f32x4 acc0[8], acc1[8];
#pragma unroll
    for (int nt = 0; nt < 8; ++nt) { acc0[nt] = bias0[nt]; acc1[nt] = bias0[nt]; }
#pragma unroll
    for (int ks = 0; ks < 2; ++ks) {
      bf16x8 bx0 = *(const bf16x8*)&xbf[(size_t)(tb + lo16) * CIN + ks * 32 + quad * 8];
      bf16x8 bx1 = *(const bf16x8*)&xbf[(size_t)(tb + 16 + lo16) * CIN + ks * 32 + quad * 8];
#pragma unroll
      for (int nt = 0; nt < 8; ++nt) {
        acc0[nt] = __builtin_amdgcn_mfma_f32_16x16x32_bf16(w0f[ks][nt], bx0, acc0[nt], 0, 0, 0);
        acc1[nt] = __builtin_amdgcn_mfma_f32_16x16x32_bf16(w0f[ks][nt], bx1, acc1[nt], 0, 0, 0);
      }
    }
    leaky_ln_store(acc0, sh, shbase + lo16, quad);
    leaky_ln_store(acc1, sh, shbase + 16 + lo16, quad);

    // ---- Layer 1: A=W1' (LDS), B=h; A-frags shared across the 2 m-tiles
#pragma unroll
    for (int nt = 0; nt < 8; ++nt) { acc0[nt] = bias1[nt]; acc1[nt] = bias1[nt]; }
#pragma unroll
    for (int ks = 0; ks < 4; ++ks) {
      bf16x8 bh0 = *(const bf16x8*)&sh[(shbase + lo16) * SH_STRIDE + ks * 32 + quad * 8];
      bf16x8 bh1 = *(const bf16x8*)&sh[(shbase + 16 + lo16) * SH_STRIDE + ks * 32 + quad * 8];
#pragma unroll
      for (int nt = 0; nt < 8; ++nt) {
        bf16x8 a = *(const bf16x8*)
            &smem[SW1_OFF + (nt * 16 + lo16) * SW1_STRIDE + ks * 32 + quad * 8];
        acc0[nt] = __builtin_amdgcn_mfma_f32_16x16x32_bf16(a, bh0, acc0[nt], 0, 0, 0);
        acc1[nt] = __builtin_amdgcn_mfma_f32_16x16x32_bf16(a, bh1, acc1[nt], 0, 0, 0);
      }
    }
    leaky_ln_store(acc0, sh, shbase + lo16, quad);
    leaky_ln_store(acc1, sh, shbase + 16 + lo16, quad);

    // ---- Layer 2: A=W2' (LDS), B=h -> C[col=token][row=f]
    f32x4 acc2a = bias2, acc2b = bias2;
#pragma unroll
    for (int ks = 0; ks < 4; ++ks) {
      bf16x8 bh0 = *(const bf16x8*)&sh[(shbase + lo16) * SH_STRIDE + ks * 32 + quad * 8];
      bf16x8 bh1 = *(const bf16x8*)&sh[(shbase + 16 + lo16) * SH_STRIDE + ks * 32 + quad * 8];
      bf16x8 a = *(const bf16x8*)
          &smem[SW2_OFF + lo16 * SW2_STRIDE + ks * 32 + quad * 8];
      acc2a = __builtin_amdgcn_mfma_f32_16x16x32_bf16(a, bh0, acc2a, 0, 0, 0);
      acc2b = __builtin_amdgcn_mfma_f32_16x16x32_bf16(a, bh1, acc2b, 0, 0, 0);
    }
    // direct fp32 out[tok][f][o] (mapping validated R6)
    {
      const size_t ta = (size_t)(tb + lo16) * (F2 * O_CH);
      const size_t tbf = (size_t)(tb + 16 + lo16) * (F2 * O_CH);
#pragma unroll
      for (int r = 0; r < 4; ++r) {
        out[ta  + (quad * 4 + r) * O_CH + o] = leaky(acc2a[r]);
        out[tbf + (quad * 4 + r) * O_CH + o] = leaky(acc2b[r]);
      }
    }
  }
}

extern "C" void kernel_launch(void* const* d_in, const int* in_sizes, int n_in,
                              void* d_out, int out_size, void* d_ws, size_t ws_size,
                              hipStream_t stream) {
  (void)in_sizes; (void)n_in; (void)out_size; (void)ws_size;
  const float* x   = (const float*)d_in[0];
  const float* W0  = (const float*)d_in[1];
  const float* b0  = (const float*)d_in[2];
  const float* g0  = (const float*)d_in[3];
  const float* be0 = (const float*)d_in[4];
  const float* W1  = (const float*)d_in[5];
  const float* b1  = (const float*)d_in[6];
  const float* g1  = (const float*)d_in[7];
  const float* be1 = (const float*)d_in[8];
  const float* W2  = (const float*)d_in[9];
  const float* b2  = (const float*)d_in[10];

  unsigned short* w0g  = (unsigned short*)((char*)d_ws + W0G_OFF);
  unsigned short* wimg = (unsigned short*)((char*)d_ws + WIMG_OFF);
  unsigned short* xbf  = (unsigned short*)((char*)d_ws + XBF_OFF);
  float* b0f = (float*)((char*)d_ws + B0F_OFF);
  float* b1f = (float*)((char*)d_ws + B1F_OFF);
  float* b2f = (float*)((char*)d_ws + B2F_OFF);

  prep<<<dim3(16 + (NTOK * CIN / 8) / 256), dim3(256), 0, stream>>>(
      x, W0, b0, g0, be0, W1, b1, g1, be1, W2, b2, w0g, wimg, xbf, b0f, b1f, b2f);
  film_main<<<dim3(O_CH * (NTOK / 256)), dim3(256), 0, stream>>>(
      xbf, w0g, wimg, b0f, b1f, b2f, (float*)d_out);
}